// Round 1
// baseline (1187.643 us; speedup 1.0000x reference)
//
#include <hip/hip_runtime.h>
#include <stdint.h>

typedef unsigned short ushort_t;
typedef __attribute__((ext_vector_type(8))) short bf8_t;     // 8 x bf16 (4 VGPRs)
typedef __attribute__((ext_vector_type(4))) float f4_t;      // MFMA accumulator
typedef __attribute__((ext_vector_type(4))) unsigned short us4_t;

#define TT 128
#define MROWS 32

__device__ __forceinline__ ushort_t f2bf(float f) {
  uint32_t u = __builtin_bit_cast(uint32_t, f);
  u += 0x7fffu + ((u >> 16) & 1u);
  return (ushort_t)(u >> 16);
}
__device__ __forceinline__ float bf2f(ushort_t h) {
  uint32_t u = ((uint32_t)h) << 16;
  return __builtin_bit_cast(float, u);
}
__device__ __forceinline__ float sigm(float x) { return 1.f / (1.f + __expf(-x)); }
__device__ __forceinline__ float tanh_f(float x) {
  float a = fabsf(x);
  float e = __expf(-2.f * a);
  float t = (1.f - e) / (1.f + e);
  return x < 0.f ? -t : t;
}

// ---------- pack kernels ----------
__global__ void k_pack_emb(const float* __restrict__ e, ushort_t* __restrict__ o) {
  int i = (blockIdx.x * 256 + threadIdx.x) * 4;
  const float4 v = *(const float4*)(e + i);
  us4_t u = { f2bf(v.x), f2bf(v.y), f2bf(v.z), f2bf(v.w) };
  *(us4_t*)(o + i) = u;
}

// W_allT[n][k] = W_g[k][j]  (n = g*256 + j), bf16, K-contiguous for MFMA frags
__global__ void k_pack_w(const float* W0, const float* W1, const float* W2, const float* W3,
                         ushort_t* __restrict__ o) {
  int idx = blockIdx.x * 256 + threadIdx.x;   // 0..262143
  int n = idx >> 8, k = idx & 255;
  int g = n >> 8, j = n & 255;
  const float* Wg = g == 0 ? W0 : g == 1 ? W1 : g == 2 ? W2 : W3;
  o[(size_t)n * 256 + k] = f2bf(Wg[k * 256 + j]);
}

// U fragment-pack: UP[((g*16+ctg)*8+kt)*64+lane][e] = U_g[kt*32+(lane>>4)*8+e][ctg*16+(lane&15)]
__global__ void k_pack_u(const float* U0, const float* U1, const float* U2, const float* U3,
                         ushort_t* __restrict__ o) {
  int idx = blockIdx.x * 256 + threadIdx.x;   // 0..32767
  int lane = idx & 63, kt = (idx >> 6) & 7, ctg = (idx >> 9) & 15, g = idx >> 13;
  const float* Ug = g == 0 ? U0 : g == 1 ? U1 : g == 2 ? U2 : U3;
  int kb = kt * 32 + (lane >> 4) * 8, col = ctg * 16 + (lane & 15);
#pragma unroll
  for (int e2 = 0; e2 < 8; ++e2)
    o[(size_t)idx * 8 + e2] = f2bf(Ug[(size_t)(kb + e2) * 256 + col]);
}

__global__ void k_bias(const float* a0, const float* a1, const float* a2, const float* a3,
                       const float* b0, const float* b1, const float* b2, const float* b3,
                       float* __restrict__ o) {
  int idx = blockIdx.x * 256 + threadIdx.x;  // 0..1023
  int g = idx >> 8, j = idx & 255;
  const float* pa = g == 0 ? a0 : g == 1 ? a1 : g == 2 ? a2 : a3;
  const float* pb = g == 0 ? b0 : g == 1 ? b1 : g == 2 ? b2 : b3;
  o[idx] = pa[j] + pb[j];
}

// ---------- K1: P = emb @ W_all  (bf16 MFMA, 128x128 tile, reg-staged LDS) ----------
__global__ __launch_bounds__(256) void k1_gemm(const ushort_t* __restrict__ A,   // emb bf16 [32000][256]
                                               const ushort_t* __restrict__ Bm,  // W_allT bf16 [1024][256]
                                               ushort_t* __restrict__ P) {       // [32000][1024]
  __shared__ ushort_t Al[128 * 32];
  __shared__ ushort_t Bl[128 * 32];
  const int tid = threadIdx.x;
  const int lane = tid & 63;
  const int w = tid >> 6;
  const int mt = blockIdx.x >> 3;
  const int nt = blockIdx.x & 7;
  const int m0 = mt * 128, n0 = nt * 128;
  const int qr = (w >> 1) * 64, qc = (w & 1) * 64;

  f4_t acc[4][4];
#pragma unroll
  for (int i = 0; i < 4; ++i)
#pragma unroll
    for (int j = 0; j < 4; ++j) acc[i][j] = f4_t{0.f, 0.f, 0.f, 0.f};

  const int r0 = tid >> 2, s0 = tid & 3;  // rows 0..63
  const int r1 = 64 + r0;                 // rows 64..127

  for (int k0 = 0; k0 < 256; k0 += 32) {
    bf8_t a0 = *(const bf8_t*)(A + (size_t)(m0 + r0) * 256 + k0 + s0 * 8);
    bf8_t a1 = *(const bf8_t*)(A + (size_t)(m0 + r1) * 256 + k0 + s0 * 8);
    bf8_t b0 = *(const bf8_t*)(Bm + (size_t)(n0 + r0) * 256 + k0 + s0 * 8);
    bf8_t b1 = *(const bf8_t*)(Bm + (size_t)(n0 + r1) * 256 + k0 + s0 * 8);
    __syncthreads();
    *(bf8_t*)(Al + (size_t)tid * 8) = a0;
    *(bf8_t*)(Al + (size_t)(256 + tid) * 8) = a1;
    *(bf8_t*)(Bl + (size_t)tid * 8) = b0;
    *(bf8_t*)(Bl + (size_t)(256 + tid) * 8) = b1;
    __syncthreads();
    bf8_t af[4], bfr[4];
#pragma unroll
    for (int i = 0; i < 4; ++i) {
      af[i]  = *(const bf8_t*)(Al + (qr + i * 16 + (lane & 15)) * 32 + (lane >> 4) * 8);
      bfr[i] = *(const bf8_t*)(Bl + (qc + i * 16 + (lane & 15)) * 32 + (lane >> 4) * 8);
    }
#pragma unroll
    for (int i = 0; i < 4; ++i)
#pragma unroll
      for (int j = 0; j < 4; ++j)
        acc[i][j] = __builtin_amdgcn_mfma_f32_16x16x32_bf16(af[i], bfr[j], acc[i][j], 0, 0, 0);
  }
#pragma unroll
  for (int i = 0; i < 4; ++i)
#pragma unroll
    for (int j = 0; j < 4; ++j)
#pragma unroll
      for (int r = 0; r < 4; ++r) {
        int row = m0 + qr + i * 16 + (lane >> 4) * 4 + r;
        int col = n0 + qc + j * 16 + (lane & 15);
        P[(size_t)row * 1024 + col] = f2bf(acc[i][j][r]);
      }
}

// ---------- K2: persistent recurrent scan ----------
// 16 teams x 4 blocks. Team owns 32 batch rows; block q owns hidden cols [q*64, q*64+64)
// for all 4 gates, with its U-slice resident in registers as MFMA B-fragments.
// Per step: h(t-1) read from L2 team buffer -> 32 MFMAs -> gates -> c,h update ->
// write h chunk -> 4-way flag barrier (double-buffered h, monotonic counter).
__global__ __launch_bounds__(512, 2) void k_scan(
    const ushort_t* __restrict__ P, const ushort_t* __restrict__ UP,
    const float* __restrict__ bias, const int* __restrict__ cap,
    ushort_t* __restrict__ hglob, float* __restrict__ hfin,
    unsigned* __restrict__ flags) {
  const int blk = blockIdx.x;
  const int team = blk >> 2, q = blk & 3;
  const int tid = threadIdx.x, lane = tid & 63, w = tid >> 6;
  const int mw = w & 1, ct = w >> 1;          // wave: m-tile (0..1) x col-tile (0..3)
  const int ctg = q * 4 + ct;                 // global 16-col tile 0..15
  const int jcol = ctg * 16 + (lane & 15);    // hidden col 0..255
  const int l16 = lane >> 4;

  // U B-fragments: uf[gate][ktile], 128 VGPRs, loaded once (coalesced, L2)
  bf8_t uf[4][8];
#pragma unroll
  for (int g = 0; g < 4; ++g)
#pragma unroll
    for (int kt = 0; kt < 8; ++kt)
      uf[g][kt] = *(const bf8_t*)(UP + ((((size_t)g * 16 + ctg) * 8 + kt) * 64 + lane) * 8);

  const float bs0 = bias[jcol], bs1 = bias[256 + jcol],
              bs2 = bias[512 + jcol], bs3 = bias[768 + jcol];

  f4_t c = {0.f, 0.f, 0.f, 0.f};
  const int rowl0 = mw * 16 + l16 * 4;        // C/D rows this lane owns (local 0..31)
  const int grow = team * MROWS + rowl0;      // global batch row
  const int arow = mw * 16 + (lane & 15);     // A-frag row (local)

  for (int t = 0; t < TT; ++t) {
    f4_t a0 = {0.f,0.f,0.f,0.f}, a1 = a0, a2 = a0, a3 = a0;
    if (t > 0) {
      const ushort_t* hr = hglob + ((size_t)team * 2 + ((t + 1) & 1)) * (MROWS * 256)
                           + (size_t)arow * 256 + l16 * 8;
      bf8_t af[8];
#pragma unroll
      for (int kt = 0; kt < 8; ++kt) af[kt] = *(const bf8_t*)(hr + kt * 32);
#pragma unroll
      for (int kt = 0; kt < 8; ++kt) {
        a0 = __builtin_amdgcn_mfma_f32_16x16x32_bf16(af[kt], uf[0][kt], a0, 0, 0, 0);
        a1 = __builtin_amdgcn_mfma_f32_16x16x32_bf16(af[kt], uf[1][kt], a1, 0, 0, 0);
        a2 = __builtin_amdgcn_mfma_f32_16x16x32_bf16(af[kt], uf[2][kt], a2, 0, 0, 0);
        a3 = __builtin_amdgcn_mfma_f32_16x16x32_bf16(af[kt], uf[3][kt], a3, 0, 0, 0);
      }
    }
    float hv[4];
#pragma unroll
    for (int r = 0; r < 4; ++r) {
      int token = cap[(grow + r) * TT + t];
      size_t pb = (size_t)token * 1024 + jcol;
      float pi = a0[r] + bf2f(P[pb])       + bs0;
      float pf = a1[r] + bf2f(P[pb + 256]) + bs1;
      float po = a2[r] + bf2f(P[pb + 512]) + bs2;
      float pg = a3[r] + bf2f(P[pb + 768]) + bs3;
      float ig = sigm(pi), fg = sigm(pf), og = sigm(po), gg = tanh_f(pg);
      float cn = ig * gg + fg * c[r];
      c[r] = cn;
      hv[r] = og * tanh_f(cn);
    }
    if (t < TT - 1) {
      ushort_t* hw = hglob + ((size_t)team * 2 + (t & 1)) * (MROWS * 256);
#pragma unroll
      for (int r = 0; r < 4; ++r) hw[(size_t)(rowl0 + r) * 256 + jcol] = f2bf(hv[r]);
      __syncthreads();                         // all block stores drained (vmcnt 0)
      if (tid == 0) {
        __threadfence();                       // write-back this XCD's L2 (cross-XCD vis)
        atomicAdd(flags + team, 1u);           // device-scope
        const unsigned tgt = 4u * (unsigned)(t + 1);
        while (__hip_atomic_load(flags + team, __ATOMIC_RELAXED, __HIP_MEMORY_SCOPE_AGENT) < tgt)
          __builtin_amdgcn_s_sleep(2);
        __threadfence();                       // invalidate stale L1/L2 before h reads
      }
      __syncthreads();
    } else {
#pragma unroll
      for (int r = 0; r < 4; ++r) hfin[(size_t)(grow + r) * 256 + jcol] = hv[r];
    }
  }
}

// ---------- K3: out = normalize(h @ fc_w + fc_b) ----------
__global__ __launch_bounds__(256) void k3_fc(const float* __restrict__ hfin,
                                             const float* __restrict__ fcw,
                                             const float* __restrict__ fcb,
                                             float* __restrict__ out) {
  __shared__ float hrow[256];
  __shared__ float red[4];
  const int b = blockIdx.x, j = threadIdx.x;
  hrow[j] = hfin[(size_t)b * 256 + j];
  __syncthreads();
  float acc = fcb[j];
#pragma unroll 4
  for (int k = 0; k < 256; ++k) acc = fmaf(hrow[k], fcw[(size_t)k * 256 + j], acc);
  float ss = acc * acc;
#pragma unroll
  for (int o = 32; o > 0; o >>= 1) ss += __shfl_down(ss, o);
  if ((j & 63) == 0) red[j >> 6] = ss;
  __syncthreads();
  float tot = red[0] + red[1] + red[2] + red[3];
  float nrm = fmaxf(sqrtf(tot), 1e-12f);
  out[(size_t)b * 256 + j] = acc / nrm;
}

extern "C" void kernel_launch(void* const* d_in, const int* in_sizes, int n_in,
                              void* d_out, int out_size, void* d_ws, size_t ws_size,
                              hipStream_t stream) {
  const int* captions = (const int*)d_in[0];
  const float* emb = (const float*)d_in[1];
  const float *W[4], *bW[4], *U[4], *bU[4];
  for (int g = 0; g < 4; ++g) {
    W[g]  = (const float*)d_in[2 + 4 * g];
    bW[g] = (const float*)d_in[3 + 4 * g];
    U[g]  = (const float*)d_in[4 + 4 * g];
    bU[g] = (const float*)d_in[5 + 4 * g];
  }
  const float* fcw = (const float*)d_in[18];
  const float* fcb = (const float*)d_in[19];
  float* out = (float*)d_out;

  char* ws = (char*)d_ws;
  ushort_t* P     = (ushort_t*)(ws);                 // 32000*1024*2 = 65,536,000
  ushort_t* embb  = (ushort_t*)(ws + 65536000);      // 32000*256*2  = 16,384,000
  ushort_t* WT    = (ushort_t*)(ws + 81920000);      // 1024*256*2   = 524,288
  ushort_t* UP    = (ushort_t*)(ws + 82444288);      // 524,288
  float*    bias  = (float*)   (ws + 82968576);      // 4,096
  ushort_t* hglob = (ushort_t*)(ws + 82972672);      // 16*2*32*256*2 = 524,288
  float*    hfin  = (float*)   (ws + 83496960);      // 512*256*4    = 524,288
  unsigned* flags = (unsigned*)(ws + 84021248);      // 256

  hipMemsetAsync(flags, 0, 256, stream);
  k_pack_emb<<<8000, 256, 0, stream>>>(emb, embb);
  k_pack_w<<<1024, 256, 0, stream>>>(W[0], W[1], W[2], W[3], WT);
  k_pack_u<<<128, 256, 0, stream>>>(U[0], U[1], U[2], U[3], UP);
  k_bias<<<4, 256, 0, stream>>>(bW[0], bW[1], bW[2], bW[3],
                                bU[0], bU[1], bU[2], bU[3], bias);
  k1_gemm<<<2000, 256, 0, stream>>>(embb, WT, P);
  k_scan<<<64, 512, 0, stream>>>(P, UP, bias, captions, hglob, hfin, flags);
  k3_fc<<<512, 256, 0, stream>>>(hfin, fcw, fcb, out);
}

// Round 2
// 828.408 us; speedup vs baseline: 1.4336x; 1.4336x over previous
//
#include <hip/hip_runtime.h>
#include <stdint.h>

typedef unsigned short ushort_t;
typedef __attribute__((ext_vector_type(8))) short bf8_t;     // 8 x bf16 (4 VGPRs)
typedef __attribute__((ext_vector_type(4))) float f4_t;      // MFMA accumulator
typedef __attribute__((ext_vector_type(4))) unsigned short us4_t;

#define TT 128
#define MROWS 32

__device__ __forceinline__ ushort_t f2bf(float f) {
  uint32_t u = __builtin_bit_cast(uint32_t, f);
  u += 0x7fffu + ((u >> 16) & 1u);
  return (ushort_t)(u >> 16);
}
__device__ __forceinline__ float bf2f(ushort_t h) {
  uint32_t u = ((uint32_t)h) << 16;
  return __builtin_bit_cast(float, u);
}
__device__ __forceinline__ float sigm(float x) { return 1.f / (1.f + __expf(-x)); }
__device__ __forceinline__ float tanh_f(float x) {
  float a = fabsf(x);
  float e = __expf(-2.f * a);
  float t = (1.f - e) / (1.f + e);
  return x < 0.f ? -t : t;
}

// ---- cache-bypass (device-coherent-point) accesses: sc0 sc1, no L2 flush/inv ----
__device__ __forceinline__ void store_bf_bypass(ushort_t* p, unsigned v) {
  asm volatile("global_store_short %0, %1, off sc0 sc1" :: "v"(p), "v"(v) : "memory");
}
__device__ __forceinline__ unsigned load_flag_bypass(const unsigned* p) {
  unsigned v;
  asm volatile("global_load_dword %0, %1, off sc0 sc1\n\ts_waitcnt vmcnt(0)"
               : "=v"(v) : "v"(p) : "memory");
  return v;
}
__device__ __forceinline__ void load_h_frags(const ushort_t* p, bf8_t f[8]) {
  asm volatile(
      "global_load_dwordx4 %0, %8, off sc0 sc1\n\t"
      "global_load_dwordx4 %1, %8, off offset:64 sc0 sc1\n\t"
      "global_load_dwordx4 %2, %8, off offset:128 sc0 sc1\n\t"
      "global_load_dwordx4 %3, %8, off offset:192 sc0 sc1\n\t"
      "global_load_dwordx4 %4, %8, off offset:256 sc0 sc1\n\t"
      "global_load_dwordx4 %5, %8, off offset:320 sc0 sc1\n\t"
      "global_load_dwordx4 %6, %8, off offset:384 sc0 sc1\n\t"
      "global_load_dwordx4 %7, %8, off offset:448 sc0 sc1\n\t"
      "s_waitcnt vmcnt(0)"
      : "=&v"(f[0]), "=&v"(f[1]), "=&v"(f[2]), "=&v"(f[3]),
        "=&v"(f[4]), "=&v"(f[5]), "=&v"(f[6]), "=&v"(f[7])
      : "v"(p)
      : "memory");
}

// ---------- pack kernels ----------
__global__ void k_pack_emb(const float* __restrict__ e, ushort_t* __restrict__ o) {
  int i = (blockIdx.x * 256 + threadIdx.x) * 4;
  const float4 v = *(const float4*)(e + i);
  us4_t u = { f2bf(v.x), f2bf(v.y), f2bf(v.z), f2bf(v.w) };
  *(us4_t*)(o + i) = u;
}

// Gate-interleaved: physical output col n = col*4 + gate.
// WT[n][k] = W_{g=n&3}[k][j=n>>2]
__global__ void k_pack_w(const float* W0, const float* W1, const float* W2, const float* W3,
                         ushort_t* __restrict__ o) {
  int idx = blockIdx.x * 256 + threadIdx.x;   // 0..262143
  int n = idx >> 8, k = idx & 255;
  int g = n & 3, j = n >> 2;
  const float* Wg = g == 0 ? W0 : g == 1 ? W1 : g == 2 ? W2 : W3;
  o[(size_t)n * 256 + k] = f2bf(Wg[k * 256 + j]);
}

// U fragment-pack: UP[((g*16+ctg)*8+kt)*64+lane][e] = U_g[kt*32+(lane>>4)*8+e][ctg*16+(lane&15)]
__global__ void k_pack_u(const float* U0, const float* U1, const float* U2, const float* U3,
                         ushort_t* __restrict__ o) {
  int idx = blockIdx.x * 256 + threadIdx.x;   // 0..32767
  int lane = idx & 63, kt = (idx >> 6) & 7, ctg = (idx >> 9) & 15, g = idx >> 13;
  const float* Ug = g == 0 ? U0 : g == 1 ? U1 : g == 2 ? U2 : U3;
  int kb = kt * 32 + (lane >> 4) * 8, col = ctg * 16 + (lane & 15);
#pragma unroll
  for (int e2 = 0; e2 < 8; ++e2)
    o[(size_t)idx * 8 + e2] = f2bf(Ug[(size_t)(kb + e2) * 256 + col]);
}

// bias2[n] (n = j*4+g) = bW_g[j] + bU_g[j]
__global__ void k_bias(const float* a0, const float* a1, const float* a2, const float* a3,
                       const float* b0, const float* b1, const float* b2, const float* b3,
                       float* __restrict__ o) {
  int n = blockIdx.x * 256 + threadIdx.x;  // 0..1023
  int g = n & 3, j = n >> 2;
  const float* pa = g == 0 ? a0 : g == 1 ? a1 : g == 2 ? a2 : a3;
  const float* pb = g == 0 ? b0 : g == 1 ? b1 : g == 2 ? b2 : b3;
  o[n] = pa[j] + pb[j];
}

// ---------- K1: P = emb @ W_all  (bf16 MFMA, 128x128 tile, reg-staged LDS) ----------
__global__ __launch_bounds__(256) void k1_gemm(const ushort_t* __restrict__ A,   // emb bf16 [32000][256]
                                               const ushort_t* __restrict__ Bm,  // WT bf16 [1024][256]
                                               ushort_t* __restrict__ P) {       // [32000][1024]
  __shared__ ushort_t Al[128 * 32];
  __shared__ ushort_t Bl[128 * 32];
  const int tid = threadIdx.x;
  const int lane = tid & 63;
  const int w = tid >> 6;
  const int mt = blockIdx.x >> 3;
  const int nt = blockIdx.x & 7;
  const int m0 = mt * 128, n0 = nt * 128;
  const int qr = (w >> 1) * 64, qc = (w & 1) * 64;

  f4_t acc[4][4];
#pragma unroll
  for (int i = 0; i < 4; ++i)
#pragma unroll
    for (int j = 0; j < 4; ++j) acc[i][j] = f4_t{0.f, 0.f, 0.f, 0.f};

  const int r0 = tid >> 2, s0 = tid & 3;  // rows 0..63
  const int r1 = 64 + r0;                 // rows 64..127

  for (int k0 = 0; k0 < 256; k0 += 32) {
    bf8_t a0 = *(const bf8_t*)(A + (size_t)(m0 + r0) * 256 + k0 + s0 * 8);
    bf8_t a1 = *(const bf8_t*)(A + (size_t)(m0 + r1) * 256 + k0 + s0 * 8);
    bf8_t b0 = *(const bf8_t*)(Bm + (size_t)(n0 + r0) * 256 + k0 + s0 * 8);
    bf8_t b1 = *(const bf8_t*)(Bm + (size_t)(n0 + r1) * 256 + k0 + s0 * 8);
    __syncthreads();
    *(bf8_t*)(Al + (size_t)tid * 8) = a0;
    *(bf8_t*)(Al + (size_t)(256 + tid) * 8) = a1;
    *(bf8_t*)(Bl + (size_t)tid * 8) = b0;
    *(bf8_t*)(Bl + (size_t)(256 + tid) * 8) = b1;
    __syncthreads();
    bf8_t af[4], bfr[4];
#pragma unroll
    for (int i = 0; i < 4; ++i) {
      af[i]  = *(const bf8_t*)(Al + (qr + i * 16 + (lane & 15)) * 32 + (lane >> 4) * 8);
      bfr[i] = *(const bf8_t*)(Bl + (qc + i * 16 + (lane & 15)) * 32 + (lane >> 4) * 8);
    }
#pragma unroll
    for (int i = 0; i < 4; ++i)
#pragma unroll
      for (int j = 0; j < 4; ++j)
        acc[i][j] = __builtin_amdgcn_mfma_f32_16x16x32_bf16(af[i], bfr[j], acc[i][j], 0, 0, 0);
  }
#pragma unroll
  for (int i = 0; i < 4; ++i)
#pragma unroll
    for (int j = 0; j < 4; ++j)
#pragma unroll
      for (int r = 0; r < 4; ++r) {
        int row = m0 + qr + i * 16 + (lane >> 4) * 4 + r;
        int col = n0 + qc + j * 16 + (lane & 15);
        P[(size_t)row * 1024 + col] = f2bf(acc[i][j][r]);
      }
}

// ---------- K2: persistent recurrent scan ----------
// 16 teams x 4 blocks; block q owns hidden cols [q*64, q*64+64) for all 4 gates,
// U slice resident in registers. Fence-free exchange: sc0/sc1 bypass accesses
// + relaxed atomic flag (no buffer_wbl2/inv -> P stays cached in L2).
__global__ __launch_bounds__(512, 2) void k_scan(
    const ushort_t* __restrict__ P, const ushort_t* __restrict__ UP,
    const float* __restrict__ bias, const int* __restrict__ cap,
    ushort_t* __restrict__ hglob, float* __restrict__ hfin,
    unsigned* __restrict__ flags) {
  const int blk = blockIdx.x;
  const int team = blk >> 2, q = blk & 3;
  const int tid = threadIdx.x, lane = tid & 63, w = tid >> 6;
  const int mw = w & 1, ct = w >> 1;          // wave: m-tile (0..1) x col-tile (0..3)
  const int ctg = q * 4 + ct;                 // global 16-col tile 0..15
  const int jcol = ctg * 16 + (lane & 15);    // hidden col 0..255
  const int l16 = lane >> 4;

  // U B-fragments: uf[gate][ktile], loaded once
  bf8_t uf[4][8];
#pragma unroll
  for (int g = 0; g < 4; ++g)
#pragma unroll
    for (int kt = 0; kt < 8; ++kt)
      uf[g][kt] = *(const bf8_t*)(UP + ((((size_t)g * 16 + ctg) * 8 + kt) * 64 + lane) * 8);

  const float4 bsv = *(const float4*)(bias + jcol * 4);
  const float bs0 = bsv.x, bs1 = bsv.y, bs2 = bsv.z, bs3 = bsv.w;

  f4_t c = {0.f, 0.f, 0.f, 0.f};
  const int rowl0 = mw * 16 + l16 * 4;        // C/D rows this lane owns (local 0..31)
  const int grow = team * MROWS + rowl0;      // global batch row
  const int arow = mw * 16 + (lane & 15);     // A-frag row (local)

  // prefetch t=0 tokens + interleaved P quad
  us4_t pf[4];
#pragma unroll
  for (int r = 0; r < 4; ++r) {
    int token = cap[(grow + r) * TT];
    pf[r] = *(const us4_t*)(P + (size_t)token * 1024 + jcol * 4);
  }

  for (int t = 0; t < TT; ++t) {
    f4_t a0 = {0.f,0.f,0.f,0.f}, a1 = a0, a2 = a0, a3 = a0;
    if (t > 0) {
      const ushort_t* hr = hglob + ((size_t)team * 2 + ((t + 1) & 1)) * (MROWS * 256)
                           + (size_t)arow * 256 + l16 * 8;
      bf8_t af[8];
      load_h_frags(hr, af);
#pragma unroll
      for (int kt = 0; kt < 8; ++kt) {
        a0 = __builtin_amdgcn_mfma_f32_16x16x32_bf16(af[kt], uf[0][kt], a0, 0, 0, 0);
        a1 = __builtin_amdgcn_mfma_f32_16x16x32_bf16(af[kt], uf[1][kt], a1, 0, 0, 0);
        a2 = __builtin_amdgcn_mfma_f32_16x16x32_bf16(af[kt], uf[2][kt], a2, 0, 0, 0);
        a3 = __builtin_amdgcn_mfma_f32_16x16x32_bf16(af[kt], uf[3][kt], a3, 0, 0, 0);
      }
    }
    float hv[4];
#pragma unroll
    for (int r = 0; r < 4; ++r) {
      float pi = a0[r] + bf2f(pf[r].x) + bs0;
      float pfv = a1[r] + bf2f(pf[r].y) + bs1;
      float po = a2[r] + bf2f(pf[r].z) + bs2;
      float pg = a3[r] + bf2f(pf[r].w) + bs3;
      float ig = sigm(pi), fg = sigm(pfv), og = sigm(po), gg = tanh_f(pg);
      float cn = ig * gg + fg * c[r];
      c[r] = cn;
      hv[r] = og * tanh_f(cn);
    }
    if (t < TT - 1) {
      ushort_t* hw = hglob + ((size_t)team * 2 + (t & 1)) * (MROWS * 256);
#pragma unroll
      for (int r = 0; r < 4; ++r)
        store_bf_bypass(hw + (size_t)(rowl0 + r) * 256 + jcol, (unsigned)f2bf(hv[r]));
      __syncthreads();                         // drains vmcnt(0): bypass stores at LLC
      // prefetch t+1 tokens + P while the flag round-trips
#pragma unroll
      for (int r = 0; r < 4; ++r) {
        int token = cap[(grow + r) * TT + t + 1];
        pf[r] = *(const us4_t*)(P + (size_t)token * 1024 + jcol * 4);
      }
      if (tid == 0) {
        atomicAdd(flags + team, 1u);           // device-coherent RMW, relaxed
        const unsigned tgt = 4u * (unsigned)(t + 1);
        while (load_flag_bypass(flags + team) < tgt)
          __builtin_amdgcn_s_sleep(2);
      }
      __syncthreads();
    } else {
#pragma unroll
      for (int r = 0; r < 4; ++r) hfin[(size_t)(grow + r) * 256 + jcol] = hv[r];
    }
  }
}

// ---------- K3: out = normalize(h @ fc_w + fc_b) ----------
__global__ __launch_bounds__(256) void k3_fc(const float* __restrict__ hfin,
                                             const float* __restrict__ fcw,
                                             const float* __restrict__ fcb,
                                             float* __restrict__ out) {
  __shared__ float hrow[256];
  __shared__ float red[4];
  const int b = blockIdx.x, j = threadIdx.x;
  hrow[j] = hfin[(size_t)b * 256 + j];
  __syncthreads();
  float acc = fcb[j];
#pragma unroll 4
  for (int k = 0; k < 256; ++k) acc = fmaf(hrow[k], fcw[(size_t)k * 256 + j], acc);
  float ss = acc * acc;
#pragma unroll
  for (int o = 32; o > 0; o >>= 1) ss += __shfl_down(ss, o);
  if ((j & 63) == 0) red[j >> 6] = ss;
  __syncthreads();
  float tot = red[0] + red[1] + red[2] + red[3];
  float nrm = fmaxf(sqrtf(tot), 1e-12f);
  out[(size_t)b * 256 + j] = acc / nrm;
}

extern "C" void kernel_launch(void* const* d_in, const int* in_sizes, int n_in,
                              void* d_out, int out_size, void* d_ws, size_t ws_size,
                              hipStream_t stream) {
  const int* captions = (const int*)d_in[0];
  const float* emb = (const float*)d_in[1];
  const float *W[4], *bW[4], *U[4], *bU[4];
  for (int g = 0; g < 4; ++g) {
    W[g]  = (const float*)d_in[2 + 4 * g];
    bW[g] = (const float*)d_in[3 + 4 * g];
    U[g]  = (const float*)d_in[4 + 4 * g];
    bU[g] = (const float*)d_in[5 + 4 * g];
  }
  const float* fcw = (const float*)d_in[18];
  const float* fcb = (const float*)d_in[19];
  float* out = (float*)d_out;

  char* ws = (char*)d_ws;
  ushort_t* P     = (ushort_t*)(ws);                 // 32000*1024*2 = 65,536,000
  ushort_t* embb  = (ushort_t*)(ws + 65536000);      // 32000*256*2  = 16,384,000
  ushort_t* WT    = (ushort_t*)(ws + 81920000);      // 1024*256*2   = 524,288
  ushort_t* UP    = (ushort_t*)(ws + 82444288);      // 524,288
  float*    bias  = (float*)   (ws + 82968576);      // 4,096
  ushort_t* hglob = (ushort_t*)(ws + 82972672);      // 16*2*32*256*2 = 524,288
  float*    hfin  = (float*)   (ws + 83496960);      // 512*256*4    = 524,288
  unsigned* flags = (unsigned*)(ws + 84021248);      // 256

  hipMemsetAsync(flags, 0, 256, stream);
  k_pack_emb<<<8000, 256, 0, stream>>>(emb, embb);
  k_pack_w<<<1024, 256, 0, stream>>>(W[0], W[1], W[2], W[3], WT);
  k_pack_u<<<128, 256, 0, stream>>>(U[0], U[1], U[2], U[3], UP);
  k_bias<<<4, 256, 0, stream>>>(bW[0], bW[1], bW[2], bW[3],
                                bU[0], bU[1], bU[2], bU[3], bias);
  k1_gemm<<<2000, 256, 0, stream>>>(embb, WT, P);
  k_scan<<<64, 512, 0, stream>>>(P, UP, bias, captions, hglob, hfin, flags);
  k3_fc<<<512, 256, 0, stream>>>(hfin, fcw, fcb, out);
}